// Round 4
// baseline (227.500 us; speedup 1.0000x reference)
//
#include <hip/hip_runtime.h>
#include <hip/hip_bf16.h>

// DIM=768, H=4, D_H=192, R_H=4, N_EXP=6, TOPK=3, BETA=0.5, BATCH=65536
// Routing is batch-independent -> fold softmax/topk/renorm/BETA into per-head
// per-expert weights c[h][e], then fold c into A, stored TRANSPOSED:
//   Ac[h][s][d] = c[h][e] * A[e][d][r],  s = e*4+r (24 slots), layout [4][24][192].
// B flat is already [24][192].
// out[b, h*192+d] = z + sum_s (sum_d' z[d']*Ac[h][s][d']) * B[s][d]
//
// Main kernel: table staged in LDS (36 KB/block). 8 lanes cooperate per
// TWO rows (R=2 row-batching: every table ds_read feeds both rows' FMAs,
// halving the LDS instruction count — round-3 was LDS-issue bound).
// Lane q owns interleaved f4 chunks d0=(8j+q)*4, j=0..5 per row.
// tmp[2][24] reduced across the 8-lane group via shfl_xor(1,2,4).
// z read from HBM once, out written once, no scratch.
// amdgpu_waves_per_eu(4,4) pins the allocator at the 128-VGPR/4-wave point
// (round-2 lesson: without it the allocator throttles to 64 VGPR and spills).

typedef float f4 __attribute__((ext_vector_type(4)));

__global__ void dff_setup(const float* __restrict__ A,
                          const float* __restrict__ Zs,
                          const float* __restrict__ Za,
                          float* __restrict__ Ac) {
  __shared__ float c[4][6];
  const int t = threadIdx.x;
  if (t < 4) {
    const int h = t;
    float cc[6] = {0.f, 0.f, 0.f, 0.f, 0.f, 0.f};
    for (int rt = 0; rt < 2; ++rt) {
      const float* Z = rt ? Za : Zs;
      float zz[6];
      float mx = -1e30f;
      for (int e = 0; e < 6; ++e) { zz[e] = Z[h * 6 + e]; mx = fmaxf(mx, zz[e]); }
      float p[6];
      float sum = 0.f;
      for (int e = 0; e < 6; ++e) { p[e] = expf(zz[e] - mx); sum += p[e]; }
      for (int e = 0; e < 6; ++e) p[e] /= sum;
      // top-3 (ties -> lowest index, matching lax.top_k)
      bool used[6] = {false, false, false, false, false, false};
      float ws = 0.f;
      int sel[3];
      float pv[3];
      for (int k = 0; k < 3; ++k) {
        int best = -1;
        float bv = -1.f;
        for (int e = 0; e < 6; ++e)
          if (!used[e] && p[e] > bv) { bv = p[e]; best = e; }
        used[best] = true;
        sel[k] = best;
        pv[k] = bv;
        ws += bv;
      }
      const float inv = 1.f / (ws + 1e-8f);
      for (int k = 0; k < 3; ++k) cc[sel[k]] += pv[k] * inv;
    }
    for (int e = 0; e < 6; ++e) c[h][e] = 0.5f * cc[e];  // BETA folded in
  }
  __syncthreads();
  // Ac[h][s][d] = c[h][e] * A[e][d][r];  A flat: A[e*768 + d*4 + r]
  for (int idx = threadIdx.x; idx < 4 * 24 * 192; idx += blockDim.x) {
    const int h = idx / (24 * 192);
    const int rem = idx % (24 * 192);
    const int s = rem / 192;
    const int d = rem % 192;
    const int e = s >> 2, r = s & 3;
    Ac[idx] = c[h][e] * A[e * 768 + d * 4 + r];
  }
}

__global__ __launch_bounds__(256)
__attribute__((amdgpu_waves_per_eu(4, 4)))
void dff_main(const float* __restrict__ z,
              const float* __restrict__ B,
              const float* __restrict__ Ac,
              float* __restrict__ out) {
  __shared__ float sA[24 * 192];   // Ac[h] slice
  __shared__ float sB[24 * 192];   // B

  const int t = threadIdx.x;               // 0..255
  const int q = t & 7;                     // eighth within row-group
  const int g = t >> 3;                    // 0..31 group id
  const int h = blockIdx.y;                // head (block-uniform)
  const int row0 = blockIdx.x * 64 + g;    // rows row0 and row0+32
  const float* __restrict__ zp0 = z + (size_t)row0 * 768 + h * 192;
  const float* __restrict__ zp1 = zp0 + 32 * 768;
  float* __restrict__ op0 = out + (size_t)row0 * 768 + h * 192;
  float* __restrict__ op1 = op0 + 32 * 768;

  // Issue z loads first so HBM latency overlaps the LDS table fill.
  // Per row: 6 interleaved f4 chunks, f4 index 8*j + q -> 24 floats each.
  f4 zv0[6], zv1[6];
#pragma unroll
  for (int j = 0; j < 6; ++j) {
    zv0[j] = reinterpret_cast<const f4*>(zp0)[8 * j + q];
    zv1[j] = reinterpret_cast<const f4*>(zp1)[8 * j + q];
  }

  // Stage table into LDS: Ac[h] (1152 f4) + B (1152 f4).
  {
    const f4* __restrict__ Ag = reinterpret_cast<const f4*>(Ac + h * (24 * 192));
    const f4* __restrict__ Bg = reinterpret_cast<const f4*>(B);
    f4* sAv = reinterpret_cast<f4*>(sA);
    f4* sBv = reinterpret_cast<f4*>(sB);
    for (int i = t; i < 1152; i += 256) {
      sAv[i] = Ag[i];
      sBv[i] = Bg[i];
    }
  }
  __syncthreads();

  float tmp0[24], tmp1[24];
#pragma unroll
  for (int s = 0; s < 24; ++s) { tmp0[s] = 0.f; tmp1[s] = 0.f; }

  // phase 1: each table read feeds BOTH rows (8 FMAs per ds_read_b128)
#pragma unroll
  for (int j = 0; j < 6; ++j) {
    const int d0 = (8 * j + q) * 4;
#pragma unroll
    for (int s = 0; s < 24; ++s) {
      const f4 a = *reinterpret_cast<const f4*>(sA + s * 192 + d0);
      tmp0[s] = fmaf(zv0[j].x, a.x,
                fmaf(zv0[j].y, a.y,
                fmaf(zv0[j].z, a.z,
                fmaf(zv0[j].w, a.w, tmp0[s]))));
      tmp1[s] = fmaf(zv1[j].x, a.x,
                fmaf(zv1[j].y, a.y,
                fmaf(zv1[j].z, a.z,
                fmaf(zv1[j].w, a.w, tmp1[s]))));
    }
  }

  // reduce tmp across the 8-lane group
#pragma unroll
  for (int s = 0; s < 24; ++s) {
    tmp0[s] += __shfl_xor(tmp0[s], 1, 64);
    tmp0[s] += __shfl_xor(tmp0[s], 2, 64);
    tmp0[s] += __shfl_xor(tmp0[s], 4, 64);
    tmp1[s] += __shfl_xor(tmp1[s], 1, 64);
    tmp1[s] += __shfl_xor(tmp1[s], 2, 64);
    tmp1[s] += __shfl_xor(tmp1[s], 4, 64);
  }

  // phase 2: out[d] = z[d] + sum_s tmp[s]*B[s][d]; each B read feeds both rows
#pragma unroll
  for (int j = 0; j < 6; ++j) {
    const int d0 = (8 * j + q) * 4;
    f4 o0 = zv0[j];
    f4 o1 = zv1[j];
#pragma unroll
    for (int s = 0; s < 24; ++s) {
      const f4 b = *reinterpret_cast<const f4*>(sB + s * 192 + d0);
      const float t0 = tmp0[s];
      const float t1 = tmp1[s];
      o0.x = fmaf(t0, b.x, o0.x);
      o0.y = fmaf(t0, b.y, o0.y);
      o0.z = fmaf(t0, b.z, o0.z);
      o0.w = fmaf(t0, b.w, o0.w);
      o1.x = fmaf(t1, b.x, o1.x);
      o1.y = fmaf(t1, b.y, o1.y);
      o1.z = fmaf(t1, b.z, o1.z);
      o1.w = fmaf(t1, b.w, o1.w);
    }
    __builtin_nontemporal_store(o0, reinterpret_cast<f4*>(op0) + 8 * j + q);
    __builtin_nontemporal_store(o1, reinterpret_cast<f4*>(op1) + 8 * j + q);
  }
}

extern "C" void kernel_launch(void* const* d_in, const int* in_sizes, int n_in,
                              void* d_out, int out_size, void* d_ws, size_t ws_size,
                              hipStream_t stream) {
  const float* z  = (const float*)d_in[0];   // [65536, 768]
  const float* A  = (const float*)d_in[1];   // [6, 192, 4]
  const float* B  = (const float*)d_in[2];   // [6, 4, 192] == [24][192]
  const float* Zs = (const float*)d_in[3];   // [4, 6]
  const float* Za = (const float*)d_in[4];   // [4, 6]
  float* out = (float*)d_out;                // [65536, 768]
  float* Ac = (float*)d_ws;                  // 4*24*192 floats = 73728 B

  dff_setup<<<1, 256, 0, stream>>>(A, Zs, Za, Ac);
  dff_main<<<dim3(1024, 4), 256, 0, stream>>>(z, B, Ac, out);
}